// Round 15
// baseline (221.980 us; speedup 1.0000x reference)
//
#include <hip/hip_runtime.h>
#include <hip/hip_bf16.h>

typedef __attribute__((ext_vector_type(8))) short short8;
typedef __attribute__((ext_vector_type(4))) float v4f;

// async global->LDS, 16B per lane. LDS dest must be wave-uniform base + lane*16.
#define ASYNC_COPY16(ldsptr, gptr)                                                        \
  __builtin_amdgcn_global_load_lds((const __attribute__((address_space(1))) void*)(gptr), \
                                   (__attribute__((address_space(3))) void*)(ldsptr),     \
                                   16, 0, 0)

__device__ __forceinline__ unsigned short f2bf(float f) {
  unsigned int u = __float_as_uint(f);
  u += 0x7fffu + ((u >> 16) & 1u);  // RNE
  return (unsigned short)(u >> 16);
}

// GEMM LDS bank swizzle (round 11, verified conflicts -> 0)
#define STAGE_SWZ(tt) ((((tt) & 3) ^ (((tt) >> 3) & 3)) * 8)
#define READ_SWZ(kb, lr) (((kb) ^ (((lr) >> 1) & 3)) * 8)

__device__ __forceinline__ void cvt_store(unsigned short* dst, float4 f0, float4 f1) {
  unsigned short v8[8] = {f2bf(f0.x), f2bf(f0.y), f2bf(f0.z), f2bf(f0.w),
                          f2bf(f1.x), f2bf(f1.y), f2bf(f1.z), f2bf(f1.w)};
  *(short8*)dst = *(short8*)v8;
}

// ---- QKV GEMM from fp32 inputs (convert fused into staging), 128x64 tiles --------
// VGPR-prefetch staging: float4 loads issued at iter top (vmcnt drains over the
// MFMA phase), cvt+ds_write after compute, single barrier. Fused rope/split/Vt
// epilogue as before.
__global__ __launch_bounds__(256, 5) void gemm_qkv(const float* __restrict__ A,
                                                   const float* __restrict__ Bm,
                                                   unsigned short* __restrict__ Q,
                                                   unsigned short* __restrict__ Ko,
                                                   unsigned short* __restrict__ Vt) {
  constexpr int Kd = 1024;
  __shared__ __attribute__((aligned(16))) unsigned short As[2 * 128 * 32];  // 16 KB
  __shared__ __attribute__((aligned(16))) unsigned short Bs[2 * 64 * 32];   //  8 KB
  int t = threadIdx.x;
  int w = t >> 6, lane = t & 63, kb = lane >> 4, lr = lane & 15;
  int m0 = blockIdx.y * 128, n0 = blockIdx.x * 64;
  int wm = (w >> 1) * 64, wn = (w & 1) * 32;
  v4f acc[4][2];
#pragma unroll
  for (int i = 0; i < 4; i++)
#pragma unroll
    for (int j = 0; j < 2; j++) acc[i][j] = (v4f){0.f, 0.f, 0.f, 0.f};
  int ra = m0 + (t >> 2);
  int rb = n0 + (t >> 2);
  int ca = STAGE_SWZ(t);
  int rs = READ_SWZ(kb, lr);
  float4 pa[4], pb[2];
  auto prefetch = [&](int it) {
    int k0 = it * 32;
    const float* a0 = A + (size_t)ra * Kd + k0 + ca;
    const float* a1 = A + (size_t)(ra + 64) * Kd + k0 + ca;
    const float* b0 = Bm + (size_t)rb * Kd + k0 + ca;
    pa[0] = *(const float4*)a0;
    pa[1] = *(const float4*)(a0 + 4);
    pa[2] = *(const float4*)a1;
    pa[3] = *(const float4*)(a1 + 4);
    pb[0] = *(const float4*)b0;
    pb[1] = *(const float4*)(b0 + 4);
  };
  auto commit = [&](int buf) {
    int abase = buf * 4096, bbase = buf * 2048;
    cvt_store(&As[abase + t * 8], pa[0], pa[1]);
    cvt_store(&As[abase + 2048 + t * 8], pa[2], pa[3]);
    cvt_store(&Bs[bbase + t * 8], pb[0], pb[1]);
  };
  prefetch(0);
  commit(0);
  __syncthreads();
  for (int it = 0; it < 32; it++) {
    int acur = (it & 1) * 4096, bcur = (it & 1) * 2048;
    if (it < 31) prefetch(it + 1);  // loads in flight across the compute phase
    short8 av[4], bv[2];
#pragma unroll
    for (int i = 0; i < 4; i++)
      av[i] = *(const short8*)&As[acur + (wm + i * 16 + lr) * 32 + rs];
#pragma unroll
    for (int j = 0; j < 2; j++)
      bv[j] = *(const short8*)&Bs[bcur + (wn + j * 16 + lr) * 32 + rs];
#pragma unroll
    for (int i = 0; i < 4; i++)
#pragma unroll
      for (int j = 0; j < 2; j++)
        acc[i][j] = __builtin_amdgcn_mfma_f32_16x16x32_bf16(av[i], bv[j], acc[i][j], 0, 0, 0);
    if (it < 31) commit((it + 1) & 1);  // vmcnt wait lands here, after compute
    __syncthreads();
  }
  // ---- fused epilogue (block-uniform type/head) ----
  int X = n0 >> 6;
  int mp = X / 6;
  int sub = X - mp * 6;
  int type = sub >> 1;  // 0=q, 1=v, 2=k
  int ii = sub & 1;
  int h = mp * 2 + ii;
  const float qs = 0.125f * 1.4426950408889634f;  // 1/sqrt(64) * log2(e)
  if (type == 1) {
#pragma unroll
    for (int i = 0; i < 4; i++) {
      int row = m0 + wm + i * 16 + kb * 4;
#pragma unroll
      for (int j = 0; j < 2; j++) {
        int dim = wn + j * 16 + lr;
#pragma unroll
        for (int r = 0; r < 4; r++) {
          int m = row + r;
          int b = m >> 11, sl = m & 2047;
          int bh = b * 16 + h;
          int p = (sl & ~31) | ((sl & 15) << 1) | ((sl >> 4) & 1);
          Vt[(size_t)bh * 131072 + (size_t)dim * 2048 + p] = f2bf(acc[i][j][r]);
        }
      }
    }
  } else {
    unsigned short* dst = (type == 0) ? Q : Ko;
    float scale = (type == 0) ? qs : 1.0f;
#pragma unroll
    for (int i = 0; i < 4; i++) {
      int row = m0 + wm + i * 16 + kb * 4;
#pragma unroll
      for (int j = 0; j < 2; j++) {
        int dim = wn + j * 16 + lr;
        float vals[4];
#pragma unroll
        for (int r = 0; r < 4; r++) vals[r] = acc[i][j][r];
        if (dim < 32) {  // rotary dims
          int jp = dim >> 1;
          float invf = expf(-(float)jp * 0.57564627324851142f);
#pragma unroll
          for (int r = 0; r < 4; r++) {
            int sl = (row + r) & 2047;
            float ang = (float)sl * invf;
            float sn, cs;
            sincosf(ang, &sn, &cs);
            float partner = __shfl_xor(vals[r], 1);
            float self = vals[r] * cs;
            vals[r] = (lr & 1) ? fmaf(partner, sn, self) : fmaf(-partner, sn, self);
          }
        }
#pragma unroll
        for (int r = 0; r < 4; r++) {
          int m = row + r;
          int b = m >> 11, sl = m & 2047;
          int bh = b * 16 + h;
          dst[(((size_t)(bh * 2048 + sl)) << 6) + dim] = f2bf(vals[r] * scale);
        }
      }
    }
  }
}

// ---------------- fused causal flash attention, v11 (unchanged) -------------------
__global__ __launch_bounds__(256, 6) void attn_fused(const unsigned short* __restrict__ Qg,
                                                     const unsigned short* __restrict__ Kg,
                                                     const unsigned short* __restrict__ Vtg,
                                                     unsigned short* __restrict__ AO,
                                                     float* __restrict__ PO,
                                                     float* __restrict__ PL) {
  __shared__ __attribute__((aligned(16))) unsigned short Ks[2 * 2048];  // 8 KB
  __shared__ __attribute__((aligned(16))) unsigned short Vs[2 * 2048];  // 8 KB
  __shared__ __attribute__((aligned(16))) unsigned short Ps[4 * 16 * 40];  // 5 KB
  int t = threadIdx.x;
  int w = t >> 6, lane = t & 63, kb = lane >> 4, lr = lane & 15;
  int gid = blockIdx.x;
  int g3 = gid & 7;
  int b2 = (gid >> 3) & 3;
  int z = (gid >> 5) & 7;
  int coset = gid >> 8;  // 0..5
  int bh = g3 * 4 + b2;
  int j = (coset == 0) ? (2 * z)
        : (coset == 1) ? (15 - 2 * z)
        : (coset == 2) ? (16 + z)
        : (coset == 3) ? (31 - z)
        : (coset == 4) ? (32 + z)
                       : (47 - z);
  int qtile, kt0, kt1, mode;  // mode 0=full, 1=lower-half, 2=upper-half
  if (j < 16)      { qtile = j;      mode = 0; kt0 = 0;          kt1 = 2 * qtile + 2; }
  else if (j < 32) { qtile = j;      mode = 1; kt0 = 0;          kt1 = qtile + 1; }
  else             { qtile = j - 16; mode = 2; kt0 = qtile + 1;  kt1 = 2 * qtile + 2; }
  int m0 = qtile * 64;
  const unsigned short* Qb = Qg + (size_t)bh * 2048 * 64;
  const unsigned short* Kb = Kg + (size_t)bh * 2048 * 64;
  const unsigned short* Vb = Vtg + (size_t)bh * 64 * 2048;

  short8 aq0 = *(const short8*)(Qb + (size_t)(m0 + w * 16 + lr) * 64 + kb * 8);
  short8 aq1 = *(const short8*)(Qb + (size_t)(m0 + w * 16 + lr) * 64 + 32 + kb * 8);

  v4f acc[4];
  float lp[4];
#pragma unroll
  for (int n = 0; n < 4; n++) acc[n] = (v4f){0.f, 0.f, 0.f, 0.f};
#pragma unroll
  for (int r = 0; r < 4; r++) lp[r] = 0.f;

  int mrow = w * 16 + kb * 4;

  int kc = t >> 5, krow_s = t & 31;
  int vc = t >> 6, vd = t & 63;
  auto stage = [&](int kt, int buf) {
    int base = buf * 2048;
    ASYNC_COPY16(&Ks[base + t * 8], Kb + (size_t)(kt * 32 + krow_s) * 64 + kc * 8);
    ASYNC_COPY16(&Vs[base + t * 8], Vb + (size_t)vd * 2048 + kt * 32 + vc * 8);
  };

  stage(kt0, 0);
  __syncthreads();

  unsigned short* Pw = &Ps[w * 640];
  int niter = kt1 - kt0;
  for (int it = 0; it < niter; it++) {
    int kt = kt0 + it;
    int cur = (it & 1) * 2048;
    if (it + 1 < niter) stage(kt + 1, (it + 1) & 1);
    v4f sc[2];
#pragma unroll
    for (int n2 = 0; n2 < 2; n2++) {
      int krow = n2 * 16 + lr;
      short8 bk0 = *(const short8*)&Ks[cur + (kb * 32 + krow) * 8];
      short8 bk1 = *(const short8*)&Ks[cur + ((kb + 4) * 32 + krow) * 8];
      v4f zz = (v4f){0.f, 0.f, 0.f, 0.f};
      zz = __builtin_amdgcn_mfma_f32_16x16x32_bf16(aq0, bk0, zz, 0, 0, 0);
      zz = __builtin_amdgcn_mfma_f32_16x16x32_bf16(aq1, bk1, zz, 0, 0, 0);
      sc[n2] = zz;
    }
    if (kt >= 2 * qtile) {
#pragma unroll
      for (int n2 = 0; n2 < 2; n2++)
#pragma unroll
        for (int r = 0; r < 4; r++) {
          int key = kt * 32 + n2 * 16 + lr;
          if (key > m0 + mrow + r) sc[n2][r] = -1e30f;
        }
    }
#pragma unroll
    for (int r = 0; r < 4; r++) {
      float p0 = exp2f(sc[0][r]);
      float p1 = exp2f(sc[1][r]);
      lp[r] += p0 + p1;
      __hip_bfloat162 pb = __float22bfloat162_rn(float2{p0, p1});
      *(__hip_bfloat162*)&Pw[(mrow & 15) * 40 + r * 40 + lr * 2] = pb;
    }
    short8 ap = *(const short8*)&Pw[lr * 40 + kb * 8];
#pragma unroll
    for (int dt = 0; dt < 4; dt++) {
      int d = dt * 16 + lr;
      short8 bv = *(const short8*)&Vs[cur + (kb * 64 + d) * 8];
      acc[dt] = __builtin_amdgcn_mfma_f32_16x16x32_bf16(ap, bv, acc[dt], 0, 0, 0);
    }
    __syncthreads();
  }
  float s[4];
#pragma unroll
  for (int r = 0; r < 4; r++) {
    s[r] = lp[r];
#pragma unroll
    for (int off = 1; off < 16; off <<= 1) s[r] += __shfl_xor(s[r], off);
  }
  if (mode == 0) {
    int b = bh >> 4, h = bh & 15;
#pragma unroll
    for (int r = 0; r < 4; r++) {
      float inv = 1.0f / s[r];
      int qrow = m0 + mrow + r;
#pragma unroll
      for (int dt = 0; dt < 4; dt++)
        AO[(size_t)(b * 2048 + qrow) * 1024 + h * 64 + dt * 16 + lr] = f2bf(acc[dt][r] * inv);
    }
  } else {
    int hf = mode - 1;
    size_t pbase = ((size_t)hf * 512 + bh * 16 + (qtile - 16)) * 4096;
    size_t plbase = (size_t)hf * 32768 + (bh * 16 + (qtile - 16)) * 64;
#pragma unroll
    for (int r = 0; r < 4; r++) {
      if (lr == 0) PL[plbase + mrow + r] = s[r];
#pragma unroll
      for (int dt = 0; dt < 4; dt++)
        PO[pbase + (size_t)(mrow + r) * 64 + dt * 16 + lr] = acc[dt][r];
    }
  }
}

// ---- out-proj GEMM with FUSED split-key combine + fp32 weight convert ------------
// Blocks with blockIdx.y in [16,32)|[48,64) cover AO rows 1024..2047 per batch:
// their A-staging reads PO0/PO1/PL and computes (a+c)/(l0+l1) inline (the
// combine kernel is gone). Other blocks stage A async from AO. B (w_out fp32)
// is converted in staging. 64x64 tiles, dbuf, single barrier.
__global__ __launch_bounds__(256, 4) void gemm_out(const unsigned short* __restrict__ AO,
                                                   const float* __restrict__ PO,
                                                   const float* __restrict__ PL,
                                                   const float* __restrict__ Bm,
                                                   float* __restrict__ C) {
  constexpr int Kd = 1024, Nd = 1024;
  __shared__ __attribute__((aligned(16))) unsigned short As[2 * 64 * 32];
  __shared__ __attribute__((aligned(16))) unsigned short Bs[2 * 64 * 32];
  int t = threadIdx.x;
  int w = t >> 6, lane = t & 63, kb = lane >> 4, lr = lane & 15;
  int m0 = blockIdx.y * 64, n0 = blockIdx.x * 64;
  bool comb = (blockIdx.y >> 4) & 1;  // rows 1024..2047 of this batch: combine path
  int wm = (w >> 1) * 32, wn = (w & 1) * 32;
  v4f acc[2][2];
#pragma unroll
  for (int i = 0; i < 2; i++)
#pragma unroll
    for (int j = 0; j < 2; j++) acc[i][j] = (v4f){0.f, 0.f, 0.f, 0.f};
  int ra = m0 + (t >> 2);
  int rb = n0 + (t >> 2);
  int ca = STAGE_SWZ(t);
  int rs = READ_SWZ(kb, lr);
  // combine-path row decomposition (lane-constant)
  int b = ra >> 11, qrow = ra & 2047;
  int q16 = (qrow >> 6) - 16, lrow = qrow & 63;
  float4 pb[2], pa0[2], pa1[2];
  float lsum = 1.0f;
  auto prefetch = [&](int it, int buf) {
    int k0 = it * 32;
    const float* b0 = Bm + (size_t)rb * Kd + k0 + ca;
    pb[0] = *(const float4*)b0;
    pb[1] = *(const float4*)(b0 + 4);
    if (comb) {
      int h = k0 >> 6, d0 = (k0 & 32) + ca;
      size_t idx = ((size_t)((b * 16 + h) * 16 + q16) * 64 + lrow) * 64 + d0;
      pa0[0] = *(const float4*)&PO[idx];
      pa0[1] = *(const float4*)&PO[idx + 4];
      pa1[0] = *(const float4*)&PO[2097152 + idx];
      pa1[1] = *(const float4*)&PO[2097152 + idx + 4];
      int pli = ((b * 16 + h) * 16 + q16) * 64 + lrow;
      lsum = PL[pli] + PL[32768 + pli];
    } else {
      ASYNC_COPY16(&As[buf * 2048 + t * 8], AO + (size_t)ra * Kd + k0 + ca);
    }
  };
  auto commit = [&](int buf) {
    cvt_store(&Bs[buf * 2048 + t * 8], pb[0], pb[1]);
    if (comb) {
      float inv = 1.0f / lsum;
      float4 f0, f1;
      f0.x = (pa0[0].x + pa1[0].x) * inv; f0.y = (pa0[0].y + pa1[0].y) * inv;
      f0.z = (pa0[0].z + pa1[0].z) * inv; f0.w = (pa0[0].w + pa1[0].w) * inv;
      f1.x = (pa0[1].x + pa1[1].x) * inv; f1.y = (pa0[1].y + pa1[1].y) * inv;
      f1.z = (pa0[1].z + pa1[1].z) * inv; f1.w = (pa0[1].w + pa1[1].w) * inv;
      cvt_store(&As[buf * 2048 + t * 8], f0, f1);
    }
  };
  prefetch(0, 0);
  commit(0);
  __syncthreads();
  for (int it = 0; it < 32; it++) {
    int cur = (it & 1) * 2048;
    if (it < 31) prefetch(it + 1, (it + 1) & 1);
    short8 av[2], bv[2];
#pragma unroll
    for (int i = 0; i < 2; i++) av[i] = *(const short8*)&As[cur + (wm + i * 16 + lr) * 32 + rs];
#pragma unroll
    for (int j = 0; j < 2; j++) bv[j] = *(const short8*)&Bs[cur + (wn + j * 16 + lr) * 32 + rs];
#pragma unroll
    for (int i = 0; i < 2; i++)
#pragma unroll
      for (int j = 0; j < 2; j++)
        acc[i][j] = __builtin_amdgcn_mfma_f32_16x16x32_bf16(av[i], bv[j], acc[i][j], 0, 0, 0);
    if (it < 31) commit((it + 1) & 1);
    __syncthreads();
  }
#pragma unroll
  for (int i = 0; i < 2; i++) {
    int row = m0 + wm + i * 16 + kb * 4;
#pragma unroll
    for (int j = 0; j < 2; j++) {
      int col = n0 + wn + j * 16 + lr;
#pragma unroll
      for (int r = 0; r < 4; r++) C[(size_t)(row + r) * Nd + col] = acc[i][j][r];
    }
  }
}

extern "C" void kernel_launch(void* const* d_in, const int* in_sizes, int n_in,
                              void* d_out, int out_size, void* d_ws, size_t ws_size,
                              hipStream_t stream) {
  const float* hidden = (const float*)d_in[0];
  const float* w_qkv = (const float*)d_in[1];
  const float* w_out = (const float*)d_in[2];
  float* out = (float*)d_out;
  char* ws = (char*)d_ws;
  unsigned short* Qb = (unsigned short*)(ws + (16ull << 20));  //  8 MB
  unsigned short* Kb = (unsigned short*)(ws + (24ull << 20));  //  8 MB
  unsigned short* Vt = (unsigned short*)(ws + (32ull << 20));  //  8 MB
  unsigned short* AO = (unsigned short*)(ws + (40ull << 20));  //  8 MB
  float* PO = (float*)(ws + (48ull << 20));                    // 16 MB
  float* PL = (float*)(ws + (64ull << 20));                    // 256 KB

  // 3 dispatches total: convert and combine are fused into the GEMMs.
  gemm_qkv<<<dim3(48, 32), 256, 0, stream>>>(hidden, w_qkv, Qb, Kb, Vt);
  attn_fused<<<1536, 256, 0, stream>>>(Qb, Kb, Vt, AO, PO, PL);
  gemm_out<<<dim3(16, 64), 256, 0, stream>>>(AO, PO, PL, w_out, out);
}

// Round 16
// 207.699 us; speedup vs baseline: 1.0688x; 1.0688x over previous
//
#include <hip/hip_runtime.h>
#include <hip/hip_bf16.h>

typedef __attribute__((ext_vector_type(8))) short short8;
typedef __attribute__((ext_vector_type(4))) float v4f;

// async global->LDS, 16B per lane. LDS dest must be wave-uniform base + lane*16.
#define ASYNC_COPY16(ldsptr, gptr)                                                        \
  __builtin_amdgcn_global_load_lds((const __attribute__((address_space(1))) void*)(gptr), \
                                   (__attribute__((address_space(3))) void*)(ldsptr),     \
                                   16, 0, 0)

__device__ __forceinline__ unsigned short f2bf(float f) {
  unsigned int u = __float_as_uint(f);
  u += 0x7fffu + ((u >> 16) & 1u);  // RNE
  return (unsigned short)(u >> 16);
}

// ---------------- fp32 -> bf16 convert: hidden + w_qkv (7.3M elems) --------------
__global__ void convert_in(const float* __restrict__ h, const float* __restrict__ wq,
                           unsigned short* __restrict__ ho, unsigned short* __restrict__ wqo) {
  int i = (blockIdx.x * blockDim.x + threadIdx.x) * 4;
  const float* src;
  unsigned short* dst;
  int j;
  if (i < 4194304) { src = h; dst = ho; j = i; }
  else { src = wq; dst = wqo; j = i - 4194304; }
  float4 v = *(const float4*)(src + j);
  ushort4 o;
  o.x = f2bf(v.x); o.y = f2bf(v.y); o.z = f2bf(v.z); o.w = f2bf(v.w);
  *(ushort4*)(dst + j) = o;
}

// GEMM LDS bank swizzle (round 11, verified conflicts -> 0)
#define STAGE_SWZ(tt) ((((tt) & 3) ^ (((tt) >> 3) & 3)) * 8)
#define READ_SWZ(kb, lr) (((kb) ^ (((lr) >> 1) & 3)) * 8)

__device__ __forceinline__ void cvt_store(unsigned short* dst, float4 f0, float4 f1) {
  unsigned short v8[8] = {f2bf(f0.x), f2bf(f0.y), f2bf(f0.z), f2bf(f0.w),
                          f2bf(f1.x), f2bf(f1.y), f2bf(f1.z), f2bf(f1.w)};
  *(short8*)dst = *(short8*)v8;
}

// ---- QKV GEMM (r13 form: bf16 in, 128x64 tiles, 12 KB LDS, 6/CU) + fused epilogue -
__global__ __launch_bounds__(256, 6) void gemm_qkv(const unsigned short* __restrict__ A,
                                                   const unsigned short* __restrict__ Bm,
                                                   unsigned short* __restrict__ Q,
                                                   unsigned short* __restrict__ Ko,
                                                   unsigned short* __restrict__ Vt) {
  constexpr int Kd = 1024;
  __shared__ __attribute__((aligned(16))) unsigned short As[128 * 32];
  __shared__ __attribute__((aligned(16))) unsigned short Bs[64 * 32];
  int t = threadIdx.x;
  int w = t >> 6, lane = t & 63, kb = lane >> 4, lr = lane & 15;
  int m0 = blockIdx.y * 128, n0 = blockIdx.x * 64;
  int wm = (w >> 1) * 64, wn = (w & 1) * 32;
  v4f acc[4][2];
#pragma unroll
  for (int i = 0; i < 4; i++)
#pragma unroll
    for (int j = 0; j < 2; j++) acc[i][j] = (v4f){0.f, 0.f, 0.f, 0.f};
  int ra = m0 + (t >> 2);
  int rb = n0 + (t >> 2);
  int ca = STAGE_SWZ(t);
  int rs = READ_SWZ(kb, lr);
  for (int k0 = 0; k0 < Kd; k0 += 32) {
    ASYNC_COPY16(&As[t * 8],        A + (size_t)ra * Kd + k0 + ca);
    ASYNC_COPY16(&As[2048 + t * 8], A + (size_t)(ra + 64) * Kd + k0 + ca);
    ASYNC_COPY16(&Bs[t * 8],        Bm + (size_t)rb * Kd + k0 + ca);
    __syncthreads();
    short8 av[4], bv[2];
#pragma unroll
    for (int i = 0; i < 4; i++) av[i] = *(const short8*)&As[(wm + i * 16 + lr) * 32 + rs];
#pragma unroll
    for (int j = 0; j < 2; j++) bv[j] = *(const short8*)&Bs[(wn + j * 16 + lr) * 32 + rs];
#pragma unroll
    for (int i = 0; i < 4; i++)
#pragma unroll
      for (int j = 0; j < 2; j++)
        acc[i][j] = __builtin_amdgcn_mfma_f32_16x16x32_bf16(av[i], bv[j], acc[i][j], 0, 0, 0);
    __syncthreads();
  }
  // ---- fused epilogue (block-uniform type/head) ----
  int X = n0 >> 6;
  int mp = X / 6;
  int sub = X - mp * 6;
  int type = sub >> 1;  // 0=q, 1=v, 2=k
  int ii = sub & 1;
  int h = mp * 2 + ii;
  const float qs = 0.125f * 1.4426950408889634f;  // 1/sqrt(64) * log2(e)
  if (type == 1) {
#pragma unroll
    for (int i = 0; i < 4; i++) {
      int row = m0 + wm + i * 16 + kb * 4;
#pragma unroll
      for (int j = 0; j < 2; j++) {
        int dim = wn + j * 16 + lr;
#pragma unroll
        for (int r = 0; r < 4; r++) {
          int m = row + r;
          int b = m >> 11, sl = m & 2047;
          int bh = b * 16 + h;
          int p = (sl & ~31) | ((sl & 15) << 1) | ((sl >> 4) & 1);
          Vt[(size_t)bh * 131072 + (size_t)dim * 2048 + p] = f2bf(acc[i][j][r]);
        }
      }
    }
  } else {
    unsigned short* dst = (type == 0) ? Q : Ko;
    float scale = (type == 0) ? qs : 1.0f;
#pragma unroll
    for (int i = 0; i < 4; i++) {
      int row = m0 + wm + i * 16 + kb * 4;
#pragma unroll
      for (int j = 0; j < 2; j++) {
        int dim = wn + j * 16 + lr;
        float vals[4];
#pragma unroll
        for (int r = 0; r < 4; r++) vals[r] = acc[i][j][r];
        if (dim < 32) {  // rotary dims
          int jp = dim >> 1;
          float invf = expf(-(float)jp * 0.57564627324851142f);
#pragma unroll
          for (int r = 0; r < 4; r++) {
            int sl = (row + r) & 2047;
            float ang = (float)sl * invf;
            float sn, cs;
            sincosf(ang, &sn, &cs);
            float partner = __shfl_xor(vals[r], 1);
            float self = vals[r] * cs;
            vals[r] = (lr & 1) ? fmaf(partner, sn, self) : fmaf(-partner, sn, self);
          }
        }
#pragma unroll
        for (int r = 0; r < 4; r++) {
          int m = row + r;
          int b = m >> 11, sl = m & 2047;
          int bh = b * 16 + h;
          dst[(((size_t)(bh * 2048 + sl)) << 6) + dim] = f2bf(vals[r] * scale);
        }
      }
    }
  }
}

// ---------------- fused causal flash attention, v11 (unchanged) -------------------
__global__ __launch_bounds__(256, 6) void attn_fused(const unsigned short* __restrict__ Qg,
                                                     const unsigned short* __restrict__ Kg,
                                                     const unsigned short* __restrict__ Vtg,
                                                     unsigned short* __restrict__ AO,
                                                     float* __restrict__ PO,
                                                     float* __restrict__ PL) {
  __shared__ __attribute__((aligned(16))) unsigned short Ks[2 * 2048];  // 8 KB
  __shared__ __attribute__((aligned(16))) unsigned short Vs[2 * 2048];  // 8 KB
  __shared__ __attribute__((aligned(16))) unsigned short Ps[4 * 16 * 40];  // 5 KB
  int t = threadIdx.x;
  int w = t >> 6, lane = t & 63, kb = lane >> 4, lr = lane & 15;
  int gid = blockIdx.x;
  int g3 = gid & 7;
  int b2 = (gid >> 3) & 3;
  int z = (gid >> 5) & 7;
  int coset = gid >> 8;  // 0..5
  int bh = g3 * 4 + b2;
  int j = (coset == 0) ? (2 * z)
        : (coset == 1) ? (15 - 2 * z)
        : (coset == 2) ? (16 + z)
        : (coset == 3) ? (31 - z)
        : (coset == 4) ? (32 + z)
                       : (47 - z);
  int qtile, kt0, kt1, mode;  // mode 0=full, 1=lower-half, 2=upper-half
  if (j < 16)      { qtile = j;      mode = 0; kt0 = 0;          kt1 = 2 * qtile + 2; }
  else if (j < 32) { qtile = j;      mode = 1; kt0 = 0;          kt1 = qtile + 1; }
  else             { qtile = j - 16; mode = 2; kt0 = qtile + 1;  kt1 = 2 * qtile + 2; }
  int m0 = qtile * 64;
  const unsigned short* Qb = Qg + (size_t)bh * 2048 * 64;
  const unsigned short* Kb = Kg + (size_t)bh * 2048 * 64;
  const unsigned short* Vb = Vtg + (size_t)bh * 64 * 2048;

  short8 aq0 = *(const short8*)(Qb + (size_t)(m0 + w * 16 + lr) * 64 + kb * 8);
  short8 aq1 = *(const short8*)(Qb + (size_t)(m0 + w * 16 + lr) * 64 + 32 + kb * 8);

  v4f acc[4];
  float lp[4];
#pragma unroll
  for (int n = 0; n < 4; n++) acc[n] = (v4f){0.f, 0.f, 0.f, 0.f};
#pragma unroll
  for (int r = 0; r < 4; r++) lp[r] = 0.f;

  int mrow = w * 16 + kb * 4;

  int kc = t >> 5, krow_s = t & 31;
  int vc = t >> 6, vd = t & 63;
  auto stage = [&](int kt, int buf) {
    int base = buf * 2048;
    ASYNC_COPY16(&Ks[base + t * 8], Kb + (size_t)(kt * 32 + krow_s) * 64 + kc * 8);
    ASYNC_COPY16(&Vs[base + t * 8], Vb + (size_t)vd * 2048 + kt * 32 + vc * 8);
  };

  stage(kt0, 0);
  __syncthreads();

  unsigned short* Pw = &Ps[w * 640];
  int niter = kt1 - kt0;
  for (int it = 0; it < niter; it++) {
    int kt = kt0 + it;
    int cur = (it & 1) * 2048;
    if (it + 1 < niter) stage(kt + 1, (it + 1) & 1);
    v4f sc[2];
#pragma unroll
    for (int n2 = 0; n2 < 2; n2++) {
      int krow = n2 * 16 + lr;
      short8 bk0 = *(const short8*)&Ks[cur + (kb * 32 + krow) * 8];
      short8 bk1 = *(const short8*)&Ks[cur + ((kb + 4) * 32 + krow) * 8];
      v4f zz = (v4f){0.f, 0.f, 0.f, 0.f};
      zz = __builtin_amdgcn_mfma_f32_16x16x32_bf16(aq0, bk0, zz, 0, 0, 0);
      zz = __builtin_amdgcn_mfma_f32_16x16x32_bf16(aq1, bk1, zz, 0, 0, 0);
      sc[n2] = zz;
    }
    if (kt >= 2 * qtile) {
#pragma unroll
      for (int n2 = 0; n2 < 2; n2++)
#pragma unroll
        for (int r = 0; r < 4; r++) {
          int key = kt * 32 + n2 * 16 + lr;
          if (key > m0 + mrow + r) sc[n2][r] = -1e30f;
        }
    }
#pragma unroll
    for (int r = 0; r < 4; r++) {
      float p0 = exp2f(sc[0][r]);
      float p1 = exp2f(sc[1][r]);
      lp[r] += p0 + p1;
      __hip_bfloat162 pb = __float22bfloat162_rn(float2{p0, p1});
      *(__hip_bfloat162*)&Pw[(mrow & 15) * 40 + r * 40 + lr * 2] = pb;
    }
    short8 ap = *(const short8*)&Pw[lr * 40 + kb * 8];
#pragma unroll
    for (int dt = 0; dt < 4; dt++) {
      int d = dt * 16 + lr;
      short8 bv = *(const short8*)&Vs[cur + (kb * 64 + d) * 8];
      acc[dt] = __builtin_amdgcn_mfma_f32_16x16x32_bf16(ap, bv, acc[dt], 0, 0, 0);
    }
    __syncthreads();
  }
  float s[4];
#pragma unroll
  for (int r = 0; r < 4; r++) {
    s[r] = lp[r];
#pragma unroll
    for (int off = 1; off < 16; off <<= 1) s[r] += __shfl_xor(s[r], off);
  }
  if (mode == 0) {
    int b = bh >> 4, h = bh & 15;
#pragma unroll
    for (int r = 0; r < 4; r++) {
      float inv = 1.0f / s[r];
      int qrow = m0 + mrow + r;
#pragma unroll
      for (int dt = 0; dt < 4; dt++)
        AO[(size_t)(b * 2048 + qrow) * 1024 + h * 64 + dt * 16 + lr] = f2bf(acc[dt][r] * inv);
    }
  } else {
    int hf = mode - 1;
    size_t pbase = ((size_t)hf * 512 + bh * 16 + (qtile - 16)) * 4096;
    size_t plbase = (size_t)hf * 32768 + (bh * 16 + (qtile - 16)) * 64;
#pragma unroll
    for (int r = 0; r < 4; r++) {
      if (lr == 0) PL[plbase + mrow + r] = s[r];
#pragma unroll
      for (int dt = 0; dt < 4; dt++)
        PO[pbase + (size_t)(mrow + r) * 64 + dt * 16 + lr] = acc[dt][r];
    }
  }
}

// ---- out-proj GEMM with FUSED split-key combine + fp32 weight convert (r15) ------
__global__ __launch_bounds__(256, 4) void gemm_out(const unsigned short* __restrict__ AO,
                                                   const float* __restrict__ PO,
                                                   const float* __restrict__ PL,
                                                   const float* __restrict__ Bm,
                                                   float* __restrict__ C) {
  constexpr int Kd = 1024, Nd = 1024;
  __shared__ __attribute__((aligned(16))) unsigned short As[2 * 64 * 32];
  __shared__ __attribute__((aligned(16))) unsigned short Bs[2 * 64 * 32];
  int t = threadIdx.x;
  int w = t >> 6, lane = t & 63, kb = lane >> 4, lr = lane & 15;
  int m0 = blockIdx.y * 64, n0 = blockIdx.x * 64;
  bool comb = (blockIdx.y >> 4) & 1;  // rows 1024..2047 of this batch: combine path
  int wm = (w >> 1) * 32, wn = (w & 1) * 32;
  v4f acc[2][2];
#pragma unroll
  for (int i = 0; i < 2; i++)
#pragma unroll
    for (int j = 0; j < 2; j++) acc[i][j] = (v4f){0.f, 0.f, 0.f, 0.f};
  int ra = m0 + (t >> 2);
  int rb = n0 + (t >> 2);
  int ca = STAGE_SWZ(t);
  int rs = READ_SWZ(kb, lr);
  int b = ra >> 11, qrow = ra & 2047;
  int q16 = (qrow >> 6) - 16, lrow = qrow & 63;
  float4 pb[2], pa0[2], pa1[2];
  float lsum = 1.0f;
  auto prefetch = [&](int it, int buf) {
    int k0 = it * 32;
    const float* b0 = Bm + (size_t)rb * Kd + k0 + ca;
    pb[0] = *(const float4*)b0;
    pb[1] = *(const float4*)(b0 + 4);
    if (comb) {
      int h = k0 >> 6, d0 = (k0 & 32) + ca;
      size_t idx = ((size_t)((b * 16 + h) * 16 + q16) * 64 + lrow) * 64 + d0;
      pa0[0] = *(const float4*)&PO[idx];
      pa0[1] = *(const float4*)&PO[idx + 4];
      pa1[0] = *(const float4*)&PO[2097152 + idx];
      pa1[1] = *(const float4*)&PO[2097152 + idx + 4];
      int pli = ((b * 16 + h) * 16 + q16) * 64 + lrow;
      lsum = PL[pli] + PL[32768 + pli];
    } else {
      ASYNC_COPY16(&As[buf * 2048 + t * 8], AO + (size_t)ra * Kd + k0 + ca);
    }
  };
  auto commit = [&](int buf) {
    cvt_store(&Bs[buf * 2048 + t * 8], pb[0], pb[1]);
    if (comb) {
      float inv = 1.0f / lsum;
      float4 f0, f1;
      f0.x = (pa0[0].x + pa1[0].x) * inv; f0.y = (pa0[0].y + pa1[0].y) * inv;
      f0.z = (pa0[0].z + pa1[0].z) * inv; f0.w = (pa0[0].w + pa1[0].w) * inv;
      f1.x = (pa0[1].x + pa1[1].x) * inv; f1.y = (pa0[1].y + pa1[1].y) * inv;
      f1.z = (pa0[1].z + pa1[1].z) * inv; f1.w = (pa0[1].w + pa1[1].w) * inv;
      cvt_store(&As[buf * 2048 + t * 8], f0, f1);
    }
  };
  prefetch(0, 0);
  commit(0);
  __syncthreads();
  for (int it = 0; it < 32; it++) {
    int cur = (it & 1) * 2048;
    if (it < 31) prefetch(it + 1, (it + 1) & 1);
    short8 av[2], bv[2];
#pragma unroll
    for (int i = 0; i < 2; i++) av[i] = *(const short8*)&As[cur + (wm + i * 16 + lr) * 32 + rs];
#pragma unroll
    for (int j = 0; j < 2; j++) bv[j] = *(const short8*)&Bs[cur + (wn + j * 16 + lr) * 32 + rs];
#pragma unroll
    for (int i = 0; i < 2; i++)
#pragma unroll
      for (int j = 0; j < 2; j++)
        acc[i][j] = __builtin_amdgcn_mfma_f32_16x16x32_bf16(av[i], bv[j], acc[i][j], 0, 0, 0);
    if (it < 31) commit((it + 1) & 1);
    __syncthreads();
  }
#pragma unroll
  for (int i = 0; i < 2; i++) {
    int row = m0 + wm + i * 16 + kb * 4;
#pragma unroll
    for (int j = 0; j < 2; j++) {
      int col = n0 + wn + j * 16 + lr;
#pragma unroll
      for (int r = 0; r < 4; r++) C[(size_t)(row + r) * Nd + col] = acc[i][j][r];
    }
  }
}

extern "C" void kernel_launch(void* const* d_in, const int* in_sizes, int n_in,
                              void* d_out, int out_size, void* d_ws, size_t ws_size,
                              hipStream_t stream) {
  const float* hidden = (const float*)d_in[0];
  const float* w_qkv = (const float*)d_in[1];
  const float* w_out = (const float*)d_in[2];
  float* out = (float*)d_out;
  char* ws = (char*)d_ws;
  unsigned short* hid_bf = (unsigned short*)(ws);                  //  8 MB
  unsigned short* wqkv_bf = (unsigned short*)(ws + (8ull << 20));  //  6 MB
  unsigned short* Qb = (unsigned short*)(ws + (16ull << 20));      //  8 MB
  unsigned short* Kb = (unsigned short*)(ws + (24ull << 20));      //  8 MB
  unsigned short* Vt = (unsigned short*)(ws + (32ull << 20));      //  8 MB
  unsigned short* AO = (unsigned short*)(ws + (40ull << 20));      //  8 MB
  float* PO = (float*)(ws + (48ull << 20));                        // 16 MB
  float* PL = (float*)(ws + (64ull << 20));                        // 256 KB

  convert_in<<<7168, 256, 0, stream>>>(hidden, w_qkv, hid_bf, wqkv_bf);
  gemm_qkv<<<dim3(48, 32), 256, 0, stream>>>(hid_bf, wqkv_bf, Qb, Kb, Vt);
  attn_fused<<<1536, 256, 0, stream>>>(Qb, Kb, Vt, AO, PO, PL);
  gemm_out<<<dim3(16, 64), 256, 0, stream>>>(AO, PO, PL, w_out, out);
}